// Round 1
// baseline (399.970 us; speedup 1.0000x reference)
//
#include <hip/hip_runtime.h>
#include <math.h>

// Problem constants (B=2, DIM=192, NH=6, HD=32, S=16, H=32, W=32, WS=4^3)
#define BB    2
#define DIMC  192
#define NHH   6
#define HDD   32
#define NPOS  16384              // S*H*W = 16*32*32
#define NWTOT 256                // windows per batch (4*8*8)
#define ATT_SCALE 0.17677669529663687f  // 32^-0.5

// ---------------------------------------------------------------------------
// 1) window avg-pool + leaky relu:  x(B,192,16,32,32) -> pooled(B,192,256)
__global__ void k_pool(const float* __restrict__ x, float* __restrict__ pooled) {
  int idx = blockIdx.x * 256 + threadIdx.x;      // [0, 2*192*256)
  if (idx >= BB * DIMC * NWTOT) return;
  int wi = idx & 255;
  int bc = idx >> 8;                              // b*192 + c
  int ws = wi >> 6, wh = (wi >> 3) & 7, ww = wi & 7;
  const float* xb = x + (size_t)bc * NPOS + (ws * 4) * 1024 + (wh * 4) * 32 + (ww * 4);
  float s = 0.f;
  for (int iz = 0; iz < 4; ++iz)
    for (int iy = 0; iy < 4; ++iy) {
      const float* r = xb + iz * 1024 + iy * 32;
      s += r[0] + r[1] + r[2] + r[3];
    }
  s *= (1.f / 64.f);
  pooled[idx] = (s >= 0.f) ? s : 0.01f * s;
}

// ---------------------------------------------------------------------------
// 2) offset / scale 1x1 convs on pooled.
//    off[(b*6+nh)*3+c3][wi] (divided by [8,8,4]), sc same layout (no div).
__global__ void k_offsc(const float* __restrict__ pooled,
                        const float* __restrict__ w_off, const float* __restrict__ b_off,
                        const float* __restrict__ w_sc, const float* __restrict__ b_sc,
                        float* __restrict__ off, float* __restrict__ sc) {
  int idx = blockIdx.x * 256 + threadIdx.x;      // [0, 2*2*18*256)
  if (idx >= BB * 2 * 18 * NWTOT) return;
  int wi = idx & 255;
  int t = idx >> 8;
  int o = t % 18; t /= 18;
  int kind = t & 1;                               // 0 = off, 1 = scale
  int b = t >> 1;
  const float* wrow = (kind ? w_sc : w_off) + o * DIMC;
  float acc = (kind ? b_sc : b_off)[o];
  const float* pb = pooled + (size_t)b * DIMC * NWTOT + wi;
  for (int c = 0; c < DIMC; ++c) acc += wrow[c] * pb[(size_t)c * NWTOT];
  int nh = o / 3, c3 = o % 3;
  size_t dst = ((size_t)(b * NHH + nh) * 3 + c3) * NWTOT + wi;
  if (!kind) {
    acc *= (c3 == 2) ? 0.25f : 0.125f;            // div by [8,8,4]
    off[dst] = acc;
  } else {
    sc[dst] = acc;
  }
}

// ---------------------------------------------------------------------------
// 3) generic fp32 GEMM  Y[b] = A(MxK) @ X[b](KxN) + bias, tiled 64x64x32
__global__ __launch_bounds__(256) void k_gemm(const float* __restrict__ A,
                                              const float* __restrict__ bias,
                                              const float* __restrict__ X,
                                              float* __restrict__ Y,
                                              int M, int K, int N,
                                              long xbs, long ybs) {
  int b = blockIdx.z;
  int m0 = blockIdx.y * 64, n0 = blockIdx.x * 64;
  const float* Xb = X + (size_t)b * xbs;
  float* Yb = Y + (size_t)b * ybs;
  __shared__ float As[64][33];
  __shared__ float Bs[32][65];
  int tid = threadIdx.x;
  int ty = tid >> 4, tx = tid & 15;
  float acc[4][4] = {};
  for (int k0 = 0; k0 < K; k0 += 32) {
    for (int i = tid; i < 64 * 32; i += 256) {
      int m = i >> 5, k = i & 31;
      As[m][k] = A[(size_t)(m0 + m) * K + k0 + k];
    }
    for (int i = tid; i < 32 * 64; i += 256) {
      int k = i >> 6, n = i & 63;
      Bs[k][n] = Xb[(size_t)(k0 + k) * N + n0 + n];
    }
    __syncthreads();
    for (int kk = 0; kk < 32; ++kk) {
      float a[4], bv[4];
#pragma unroll
      for (int r = 0; r < 4; ++r) a[r] = As[ty * 4 + r][kk];
#pragma unroll
      for (int c = 0; c < 4; ++c) bv[c] = Bs[kk][tx * 4 + c];
#pragma unroll
      for (int r = 0; r < 4; ++r)
#pragma unroll
        for (int c = 0; c < 4; ++c) acc[r][c] += a[r] * bv[c];
    }
    __syncthreads();
  }
  for (int r = 0; r < 4; ++r) {
    float bb = bias ? bias[m0 + ty * 4 + r] : 0.f;
    for (int c = 0; c < 4; ++c)
      Yb[(size_t)(m0 + ty * 4 + r) * N + n0 + tx * 4 + c] = acc[r][c] + bb;
  }
}

// ---------------------------------------------------------------------------
// 4) deformable grid-sample of K and V (fused grid computation).
//    qkv layout (B, 576, NPOS); k section channels 192.., v section 384..
__global__ void k_sample(const float* __restrict__ qkv,
                         const float* __restrict__ off, const float* __restrict__ sc,
                         float* __restrict__ ks, float* __restrict__ vs) {
  int idx = blockIdx.x * 256 + threadIdx.x;      // [0, 12*NPOS)
  int p = idx & (NPOS - 1);
  int bnh = idx >> 14;
  if (bnh >= BB * NHH) return;
  int b = bnh / NHH, nh = bnh % NHH;
  int s = p >> 10, h = (p >> 5) & 31, w = p & 31;
  int ws = s >> 2, wh = h >> 2, ww = w >> 2;
  int is = s & 3, ih = h & 3, iw = w & 3;
  int wi = ws * 64 + wh * 8 + ww;
  const float* ob = off + (size_t)(bnh * 3) * NWTOT + wi;
  const float* sb = sc + (size_t)(bnh * 3) * NWTOT + wi;
  float o0 = ob[0], o1 = ob[NWTOT], o2 = ob[2 * NWTOT];
  float s0 = sb[0], s1 = sb[NWTOT], s2 = sb[2 * NWTOT];
  float gxn = -1.f + 2.f * w / 31.f + ((2.f * iw - 3.f) / 31.f) * s0 + o0;
  float gyn = -1.f + 2.f * h / 31.f + ((2.f * ih - 3.f) / 31.f) * s1 + o1;
  float gzn = -1.f + 2.f * s / 15.f + ((2.f * is - 3.f) / 15.f) * s2 + o2;
  float gx = (gxn + 1.f) * 15.5f;
  float gy = (gyn + 1.f) * 15.5f;
  float gz = (gzn + 1.f) * 7.5f;
  float x0f = floorf(gx), y0f = floorf(gy), z0f = floorf(gz);
  float fx = gx - x0f, fy = gy - y0f, fz = gz - z0f;
  int x0 = (int)x0f, y0 = (int)y0f, z0 = (int)z0f;
  int cidx[8];
  float cw[8];
  int n = 0;
  for (int dz = 0; dz < 2; ++dz)
    for (int dy = 0; dy < 2; ++dy)
      for (int dx = 0; dx < 2; ++dx) {
        int zz = z0 + dz, yy = y0 + dy, xx = x0 + dx;
        bool valid = (zz >= 0 && zz < 16 && yy >= 0 && yy < 32 && xx >= 0 && xx < 32);
        int zc = min(max(zz, 0), 15), yc = min(max(yy, 0), 31), xc = min(max(xx, 0), 31);
        float wgt = (dz ? fz : 1.f - fz) * (dy ? fy : 1.f - fy) * (dx ? fx : 1.f - fx);
        cidx[n] = zc * 1024 + yc * 32 + xc;
        cw[n] = valid ? wgt : 0.f;
        ++n;
      }
  const float* kbase = qkv + ((size_t)b * 576 + 192 + nh * 32) * NPOS;
  const float* vbase = qkv + ((size_t)b * 576 + 384 + nh * 32) * NPOS;
  float* kout = ks + (size_t)bnh * 32 * NPOS + p;
  float* vout = vs + (size_t)bnh * 32 * NPOS + p;
  for (int hd = 0; hd < 32; ++hd) {
    const float* kc = kbase + (size_t)hd * NPOS;
    const float* vc = vbase + (size_t)hd * NPOS;
    float ak = 0.f, av = 0.f;
#pragma unroll
    for (int j = 0; j < 8; ++j) {
      ak += cw[j] * kc[cidx[j]];
      av += cw[j] * vc[cidx[j]];
    }
    kout[(size_t)hd * NPOS] = ak;
    vout[(size_t)hd * NPOS] = av;
  }
}

// ---------------------------------------------------------------------------
// 5) windowed attention. One block per (window, head). Output written in
//    (B,192,S,H,W) layout into the q-section of qkvio (safe: each element is
//    read (as Q) and written (as out) only by this block, barrier between).
__global__ __launch_bounds__(256) void k_attn(float* qkvio,
                                              const float* __restrict__ ks,
                                              const float* __restrict__ vs,
                                              const float* __restrict__ rpb_table) {
  __shared__ float Q[64][33], K[64][33], V[64][33];
  __shared__ float Aw[64][65];
  __shared__ float rpb[343 * 6];
  int blk = blockIdx.x;                          // [0, 512*6)
  int nh = blk % 6;
  int wid = blk / 6;
  int b = wid >> 8;
  int win = wid & 255;
  int ws = win >> 6, wh = (win >> 3) & 7, ww = win & 7;
  int bnh = b * NHH + nh;
  int tid = threadIdx.x;
  for (int i = tid; i < 343 * 6; i += 256) rpb[i] = rpb_table[i];
  int pbase = (ws * 4) * 1024 + (wh * 4) * 32 + (ww * 4);
  const float* qb = qkvio + ((size_t)b * 576 + nh * 32) * NPOS;
  const float* kb = ks + (size_t)bnh * 32 * NPOS;
  const float* vb = vs + (size_t)bnh * 32 * NPOS;
  for (int i = tid; i < 64 * 32; i += 256) {
    int t = i & 63, hd = i >> 6;
    int pp = pbase + (t >> 4) * 1024 + ((t >> 2) & 3) * 32 + (t & 3);
    Q[t][hd] = qb[(size_t)hd * NPOS + pp];
    K[t][hd] = kb[(size_t)hd * NPOS + pp];
    V[t][hd] = vb[(size_t)hd * NPOS + pp];
  }
  __syncthreads();
  // scores + relative position bias
  for (int i = tid; i < 4096; i += 256) {
    int qt = i >> 6, kt = i & 63;
    float acc = 0.f;
#pragma unroll
    for (int d = 0; d < 32; ++d) acc += Q[qt][d] * K[kt][d];
    int qis = qt >> 4, qih = (qt >> 2) & 3, qiw = qt & 3;
    int kis = kt >> 4, kih = (kt >> 2) & 3, kiw = kt & 3;
    int ridx = (qis - kis + 3) * 11 + (qih - kih + 3) * 7 + (qiw - kiw + 3);
    Aw[qt][kt] = acc * ATT_SCALE + rpb[ridx * 6 + nh];
  }
  __syncthreads();
  // softmax: 4 lanes per row
  {
    int r = tid >> 2, q4 = tid & 3;
    float m = -1e30f;
    for (int j = 0; j < 16; ++j) m = fmaxf(m, Aw[r][q4 * 16 + j]);
    m = fmaxf(m, __shfl_xor(m, 1));
    m = fmaxf(m, __shfl_xor(m, 2));
    float ssum = 0.f;
    for (int j = 0; j < 16; ++j) {
      float e = __expf(Aw[r][q4 * 16 + j] - m);
      Aw[r][q4 * 16 + j] = e;
      ssum += e;
    }
    ssum += __shfl_xor(ssum, 1);
    ssum += __shfl_xor(ssum, 2);
    float inv = 1.f / ssum;
    for (int j = 0; j < 16; ++j) Aw[r][q4 * 16 + j] *= inv;
  }
  __syncthreads();
  // out = attn @ V, write back into q-section in (B,192,S,H,W) layout
  float* outc = qkvio + ((size_t)b * 576 + nh * 32) * NPOS;
  for (int i = tid; i < 2048; i += 256) {
    int qt = i & 63, hd = i >> 6;
    float acc = 0.f;
#pragma unroll
    for (int kt = 0; kt < 64; ++kt) acc += Aw[qt][kt] * V[kt][hd];
    int pp = pbase + (qt >> 4) * 1024 + ((qt >> 2) & 3) * 32 + (qt & 3);
    outc[(size_t)hd * NPOS + pp] = acc;
  }
}

// ---------------------------------------------------------------------------
extern "C" void kernel_launch(void* const* d_in, const int* in_sizes, int n_in,
                              void* d_out, int out_size, void* d_ws, size_t ws_size,
                              hipStream_t stream) {
  const float* x      = (const float*)d_in[0];
  // d_in[1] = x_up (unused by reference)
  const float* w_qkv  = (const float*)d_in[2];
  const float* b_qkv  = (const float*)d_in[3];
  const float* w_off  = (const float*)d_in[4];
  const float* b_off  = (const float*)d_in[5];
  const float* w_sc   = (const float*)d_in[6];
  const float* b_sc   = (const float*)d_in[7];
  const float* w_proj = (const float*)d_in[8];
  const float* b_proj = (const float*)d_in[9];
  const float* rpb    = (const float*)d_in[10];
  float* out = (float*)d_out;
  float* ws = (float*)d_ws;

  float* qkv    = ws;                                    // 2*576*16384 floats
  float* ks     = qkv + (size_t)BB * 576 * NPOS;         // 12*32*16384
  float* vs     = ks + (size_t)BB * NHH * HDD * NPOS;    // 12*32*16384
  float* pooled = vs + (size_t)BB * NHH * HDD * NPOS;    // 2*192*256
  float* offb   = pooled + (size_t)BB * DIMC * NWTOT;    // 12*3*256
  float* scb    = offb + (size_t)BB * NHH * 3 * NWTOT;   // 12*3*256

  k_pool<<<384, 256, 0, stream>>>(x, pooled);
  k_offsc<<<72, 256, 0, stream>>>(pooled, w_off, b_off, w_sc, b_sc, offb, scb);
  k_gemm<<<dim3(NPOS / 64, 576 / 64, BB), 256, 0, stream>>>(
      w_qkv, b_qkv, x, qkv, 576, DIMC, NPOS,
      (long)DIMC * NPOS, (long)576 * NPOS);
  k_sample<<<768, 256, 0, stream>>>(qkv, offb, scb, ks, vs);
  k_attn<<<BB * NWTOT * NHH, 256, 0, stream>>>(qkv, ks, vs, rpb);
  k_gemm<<<dim3(NPOS / 64, DIMC / 64, BB), 256, 0, stream>>>(
      w_proj, b_proj, qkv, out, DIMC, DIMC, NPOS,
      (long)576 * NPOS, (long)DIMC * NPOS);
}

// Round 2
// 220.109 us; speedup vs baseline: 1.8171x; 1.8171x over previous
//
#include <hip/hip_runtime.h>
#include <math.h>

// Problem constants (B=2, DIM=192, NH=6, HD=32, S=16, H=32, W=32, WS=4^3)
#define BB    2
#define DIMC  192
#define NHH   6
#define HDD   32
#define NPOS  16384              // S*H*W
#define NWTOT 256                // windows per batch
#define ATT_SCALE 0.17677669529663687f  // 32^-0.5

typedef _Float16 f16x8 __attribute__((ext_vector_type(8)));
typedef float f32x4 __attribute__((ext_vector_type(4)));

// ---------------------------------------------------------------------------
// 0a) fp32 -> fp16 weight conversion (w_qkv 576x192, w_proj 192x192)
__global__ void k_cvtw(const float* __restrict__ wq, const float* __restrict__ wp,
                       _Float16* __restrict__ whq, _Float16* __restrict__ whp) {
  int i = blockIdx.x * 256 + threadIdx.x;
  if (i < 576 * DIMC) whq[i] = (_Float16)wq[i];
  else {
    int j = i - 576 * DIMC;
    if (j < DIMC * DIMC) whp[j] = (_Float16)wp[j];
  }
}

// 0b) transpose x (B,192,16384) fp32 -> Xt (B,16384,192) fp16
//     thread handles 8 consecutive channels for one position (16B store).
__global__ void k_transx(const float* __restrict__ x, _Float16* __restrict__ xt) {
  int idx = blockIdx.x * 256 + threadIdx.x;   // [0, 2*24*16384)
  int p = idx & (NPOS - 1);
  int t = idx >> 14;
  int cseg = t % 24;
  int b = t / 24;
  if (b >= BB) return;
  const float* src = x + ((size_t)b * DIMC + cseg * 8) * NPOS + p;
  _Float16 v[8];
#pragma unroll
  for (int j = 0; j < 8; ++j) v[j] = (_Float16)src[(size_t)j * NPOS];
  *(uint4*)(xt + ((size_t)b * NPOS + p) * DIMC + cseg * 8) = *(uint4*)v;
}

// ---------------------------------------------------------------------------
// 1) window avg-pool + leaky relu
__global__ void k_pool(const float* __restrict__ x, float* __restrict__ pooled) {
  int idx = blockIdx.x * 256 + threadIdx.x;
  if (idx >= BB * DIMC * NWTOT) return;
  int wi = idx & 255;
  int bc = idx >> 8;
  int ws = wi >> 6, wh = (wi >> 3) & 7, ww = wi & 7;
  const float* xb = x + (size_t)bc * NPOS + (ws * 4) * 1024 + (wh * 4) * 32 + (ww * 4);
  float s = 0.f;
  for (int iz = 0; iz < 4; ++iz)
    for (int iy = 0; iy < 4; ++iy) {
      const float* r = xb + iz * 1024 + iy * 32;
      s += r[0] + r[1] + r[2] + r[3];
    }
  s *= (1.f / 64.f);
  pooled[idx] = (s >= 0.f) ? s : 0.01f * s;
}

// ---------------------------------------------------------------------------
// 2) offset / scale 1x1 convs on pooled
__global__ void k_offsc(const float* __restrict__ pooled,
                        const float* __restrict__ w_off, const float* __restrict__ b_off,
                        const float* __restrict__ w_sc, const float* __restrict__ b_sc,
                        float* __restrict__ off, float* __restrict__ sc) {
  int idx = blockIdx.x * 256 + threadIdx.x;
  if (idx >= BB * 2 * 18 * NWTOT) return;
  int wi = idx & 255;
  int t = idx >> 8;
  int o = t % 18; t /= 18;
  int kind = t & 1;
  int b = t >> 1;
  const float* wrow = (kind ? w_sc : w_off) + o * DIMC;
  float acc = (kind ? b_sc : b_off)[o];
  const float* pb = pooled + (size_t)b * DIMC * NWTOT + wi;
  for (int c = 0; c < DIMC; ++c) acc += wrow[c] * pb[(size_t)c * NWTOT];
  int nh = o / 3, c3 = o % 3;
  size_t dst = ((size_t)(b * NHH + nh) * 3 + c3) * NWTOT + wi;
  if (!kind) {
    acc *= (c3 == 2) ? 0.25f : 0.125f;
    off[dst] = acc;
  } else {
    sc[dst] = acc;
  }
}

// ---------------------------------------------------------------------------
// 3) fp16 MFMA GEMM:  Y[b](MxN) = A(MxK=192) @ Bm[b]^T + bias
//    A: [M][192] halfs (k-contiguous). Bm: [b][N][192] halfs (k-contiguous).
//    Tile 64x128x64, 4 waves (2x2), each wave 32x64 via 16x16x32 MFMA.
//    LDS XOR-swizzle byte ^= ((row&7)<<4) -> frag b128 reads spread 8 lanes
//    per 16B slot (uniform => throughput-optimal).
__global__ __launch_bounds__(256) void k_gemm16(
    const _Float16* __restrict__ A, const float* __restrict__ bias,
    const _Float16* __restrict__ Bm, float* __restrict__ Y, int M, int N) {
  const int K = DIMC;
  int bz = blockIdx.z;
  int n0 = blockIdx.x * 128, m0 = blockIdx.y * 64;
  const _Float16* Bb = Bm + (size_t)bz * N * K;
  float* Yb = Y + (size_t)bz * M * N;
  __shared__ _Float16 Al[64 * 64];    // swizzled [m][k]
  __shared__ _Float16 Bl[128 * 64];   // swizzled [n][k]
  int tid = threadIdx.x;
  int wave = tid >> 6, lane = tid & 63;
  int wm = wave >> 1, wn = wave & 1;
  int lrow = lane & 15, lkg = lane >> 4;
  f32x4 acc[2][4] = {};
  for (int k0 = 0; k0 < K; k0 += 64) {
    for (int c = tid; c < 512; c += 256) {           // A tile: 64 rows x 8 segs
      int r = c >> 3, seg = c & 7;
      uint4 v = *(const uint4*)(A + (size_t)(m0 + r) * K + k0 + seg * 8);
      *(uint4*)((char*)Al + r * 128 + ((seg * 16) ^ ((r & 7) << 4))) = v;
    }
    for (int c = tid; c < 1024; c += 256) {          // B tile: 128 rows x 8 segs
      int r = c >> 3, seg = c & 7;
      uint4 v = *(const uint4*)(Bb + (size_t)(n0 + r) * K + k0 + seg * 8);
      *(uint4*)((char*)Bl + r * 128 + ((seg * 16) ^ ((r & 7) << 4))) = v;
    }
    __syncthreads();
#pragma unroll
    for (int ks = 0; ks < 2; ++ks) {
      f16x8 af[2], bf[4];
#pragma unroll
      for (int mf = 0; mf < 2; ++mf) {
        int row = wm * 32 + mf * 16 + lrow;
        af[mf] = *(const f16x8*)((const char*)Al + row * 128 +
                                 ((ks * 64 + lkg * 16) ^ ((row & 7) << 4)));
      }
#pragma unroll
      for (int nf = 0; nf < 4; ++nf) {
        int row = wn * 64 + nf * 16 + lrow;
        bf[nf] = *(const f16x8*)((const char*)Bl + row * 128 +
                                 ((ks * 64 + lkg * 16) ^ ((row & 7) << 4)));
      }
#pragma unroll
      for (int mf = 0; mf < 2; ++mf)
#pragma unroll
        for (int nf = 0; nf < 4; ++nf)
          acc[mf][nf] = __builtin_amdgcn_mfma_f32_16x16x32_f16(af[mf], bf[nf], acc[mf][nf], 0, 0, 0);
    }
    __syncthreads();
  }
  int crow = (lane >> 4) * 4, ccol = lane & 15;
#pragma unroll
  for (int mf = 0; mf < 2; ++mf)
#pragma unroll
    for (int nf = 0; nf < 4; ++nf) {
      int m = m0 + wm * 32 + mf * 16 + crow;
      int n = n0 + wn * 64 + nf * 16 + ccol;
#pragma unroll
      for (int r = 0; r < 4; ++r)
        Yb[(size_t)(m + r) * N + n] = acc[mf][nf][r] + bias[m + r];
    }
}

// ---------------------------------------------------------------------------
// 4) deformable grid-sample of K and V (fp16 output)
__global__ void k_sample(const float* __restrict__ qkv,
                         const float* __restrict__ off, const float* __restrict__ sc,
                         _Float16* __restrict__ ks, _Float16* __restrict__ vs) {
  int idx = blockIdx.x * 256 + threadIdx.x;
  int p = idx & (NPOS - 1);
  int bnh = idx >> 14;
  if (bnh >= BB * NHH) return;
  int b = bnh / NHH, nh = bnh % NHH;
  int s = p >> 10, h = (p >> 5) & 31, w = p & 31;
  int is = s & 3, ih = h & 3, iw = w & 3;
  int wi = (s >> 2) * 64 + (h >> 2) * 8 + (w >> 2);
  const float* ob = off + (size_t)(bnh * 3) * NWTOT + wi;
  const float* sb = sc + (size_t)(bnh * 3) * NWTOT + wi;
  float gxn = -1.f + 2.f * w / 31.f + ((2.f * iw - 3.f) / 31.f) * sb[0] + ob[0];
  float gyn = -1.f + 2.f * h / 31.f + ((2.f * ih - 3.f) / 31.f) * sb[NWTOT] + ob[NWTOT];
  float gzn = -1.f + 2.f * s / 15.f + ((2.f * is - 3.f) / 15.f) * sb[2 * NWTOT] + ob[2 * NWTOT];
  float gx = (gxn + 1.f) * 15.5f;
  float gy = (gyn + 1.f) * 15.5f;
  float gz = (gzn + 1.f) * 7.5f;
  float x0f = floorf(gx), y0f = floorf(gy), z0f = floorf(gz);
  float fx = gx - x0f, fy = gy - y0f, fz = gz - z0f;
  int x0 = (int)x0f, y0 = (int)y0f, z0 = (int)z0f;
  int cidx[8];
  float cw[8];
  int n = 0;
  for (int dz = 0; dz < 2; ++dz)
    for (int dy = 0; dy < 2; ++dy)
      for (int dx = 0; dx < 2; ++dx) {
        int zz = z0 + dz, yy = y0 + dy, xx = x0 + dx;
        bool valid = (zz >= 0 && zz < 16 && yy >= 0 && yy < 32 && xx >= 0 && xx < 32);
        int zc = min(max(zz, 0), 15), yc = min(max(yy, 0), 31), xc = min(max(xx, 0), 31);
        float wgt = (dz ? fz : 1.f - fz) * (dy ? fy : 1.f - fy) * (dx ? fx : 1.f - fx);
        cidx[n] = zc * 1024 + yc * 32 + xc;
        cw[n] = valid ? wgt : 0.f;
        ++n;
      }
  const float* kbase = qkv + ((size_t)b * 576 + 192 + nh * 32) * NPOS;
  const float* vbase = qkv + ((size_t)b * 576 + 384 + nh * 32) * NPOS;
  _Float16* kout = ks + (size_t)bnh * 32 * NPOS + p;
  _Float16* vout = vs + (size_t)bnh * 32 * NPOS + p;
  for (int hd = 0; hd < 32; ++hd) {
    const float* kc = kbase + (size_t)hd * NPOS;
    const float* vc = vbase + (size_t)hd * NPOS;
    float ak = 0.f, av = 0.f;
#pragma unroll
    for (int j = 0; j < 8; ++j) {
      ak += cw[j] * kc[cidx[j]];
      av += cw[j] * vc[cidx[j]];
    }
    kout[(size_t)hd * NPOS] = (_Float16)ak;
    vout[(size_t)hd * NPOS] = (_Float16)av;
  }
}

// ---------------------------------------------------------------------------
// 5) windowed attention. Output written fp16 in [b][pos][192] layout (= proj
//    GEMM's k-contiguous B layout).
__global__ __launch_bounds__(256) void k_attn(const float* __restrict__ qkv,
                                              const _Float16* __restrict__ ks,
                                              const _Float16* __restrict__ vs,
                                              const float* __restrict__ rpb_table,
                                              _Float16* __restrict__ pin) {
  __shared__ float Q[64][33], K[64][33], V[64][33];
  __shared__ float Aw[64][65];
  __shared__ float rpb[343 * 6];
  int blk = blockIdx.x;
  int nh = blk % 6;
  int wid = blk / 6;
  int b = wid >> 8;
  int win = wid & 255;
  int ws = win >> 6, wh = (win >> 3) & 7, ww = win & 7;
  int bnh = b * NHH + nh;
  int tid = threadIdx.x;
  for (int i = tid; i < 343 * 6; i += 256) rpb[i] = rpb_table[i];
  int pbase = (ws * 4) * 1024 + (wh * 4) * 32 + (ww * 4);
  const float* qb = qkv + ((size_t)b * 576 + nh * 32) * NPOS;
  const _Float16* kb = ks + (size_t)bnh * 32 * NPOS;
  const _Float16* vb = vs + (size_t)bnh * 32 * NPOS;
  for (int i = tid; i < 64 * 32; i += 256) {
    int t = i & 63, hd = i >> 6;
    int pp = pbase + (t >> 4) * 1024 + ((t >> 2) & 3) * 32 + (t & 3);
    Q[t][hd] = qb[(size_t)hd * NPOS + pp];
    K[t][hd] = (float)kb[(size_t)hd * NPOS + pp];
    V[t][hd] = (float)vb[(size_t)hd * NPOS + pp];
  }
  __syncthreads();
  for (int i = tid; i < 4096; i += 256) {
    int qt = i >> 6, kt = i & 63;
    float acc = 0.f;
#pragma unroll
    for (int d = 0; d < 32; ++d) acc += Q[qt][d] * K[kt][d];
    int qis = qt >> 4, qih = (qt >> 2) & 3, qiw = qt & 3;
    int kis = kt >> 4, kih = (kt >> 2) & 3, kiw = kt & 3;
    int ridx = (qis - kis + 3) * 11 + (qih - kih + 3) * 7 + (qiw - kiw + 3);
    Aw[qt][kt] = acc * ATT_SCALE + rpb[ridx * 6 + nh];
  }
  __syncthreads();
  {
    int r = tid >> 2, q4 = tid & 3;
    float m = -1e30f;
    for (int j = 0; j < 16; ++j) m = fmaxf(m, Aw[r][q4 * 16 + j]);
    m = fmaxf(m, __shfl_xor(m, 1));
    m = fmaxf(m, __shfl_xor(m, 2));
    float ssum = 0.f;
    for (int j = 0; j < 16; ++j) {
      float e = __expf(Aw[r][q4 * 16 + j] - m);
      Aw[r][q4 * 16 + j] = e;
      ssum += e;
    }
    ssum += __shfl_xor(ssum, 1);
    ssum += __shfl_xor(ssum, 2);
    float inv = 1.f / ssum;
    for (int j = 0; j < 16; ++j) Aw[r][q4 * 16 + j] *= inv;
  }
  __syncthreads();
  // out = attn @ V -> pin[b][pos][nh*32+hd] fp16 (k-contiguous for proj GEMM)
  for (int i = tid; i < 2048; i += 256) {
    int hd = i & 31, qt = i >> 5;
    float acc = 0.f;
#pragma unroll
    for (int kt = 0; kt < 64; ++kt) acc += Aw[qt][kt] * V[kt][hd];
    int pp = pbase + (qt >> 4) * 1024 + ((qt >> 2) & 3) * 32 + (qt & 3);
    pin[((size_t)b * NPOS + pp) * DIMC + nh * 32 + hd] = (_Float16)acc;
  }
}

// ---------------------------------------------------------------------------
extern "C" void kernel_launch(void* const* d_in, const int* in_sizes, int n_in,
                              void* d_out, int out_size, void* d_ws, size_t ws_size,
                              hipStream_t stream) {
  const float* x      = (const float*)d_in[0];
  const float* w_qkv  = (const float*)d_in[2];
  const float* b_qkv  = (const float*)d_in[3];
  const float* w_off  = (const float*)d_in[4];
  const float* b_off  = (const float*)d_in[5];
  const float* w_sc   = (const float*)d_in[6];
  const float* b_sc   = (const float*)d_in[7];
  const float* w_proj = (const float*)d_in[8];
  const float* b_proj = (const float*)d_in[9];
  const float* rpb    = (const float*)d_in[10];
  float* out = (float*)d_out;
  char* ws = (char*)d_ws;

  float*    qkv = (float*)ws;                           ws += (size_t)BB * 576 * NPOS * 4;
  _Float16* ksb = (_Float16*)ws;                        ws += (size_t)BB * NHH * HDD * NPOS * 2;
  _Float16* vsb = (_Float16*)ws;                        ws += (size_t)BB * NHH * HDD * NPOS * 2;
  _Float16* xt  = (_Float16*)ws;                        ws += (size_t)BB * NPOS * DIMC * 2;
  _Float16* pin = xt;   // aliased: xt dead after qkv GEMM, pin written by k_attn
  _Float16* whq = (_Float16*)ws;                        ws += (size_t)576 * DIMC * 2;
  _Float16* whp = (_Float16*)ws;                        ws += (size_t)DIMC * DIMC * 2;
  float* pooled = (float*)ws;                           ws += (size_t)BB * DIMC * NWTOT * 4;
  float* offb   = (float*)ws;                           ws += (size_t)BB * NHH * 3 * NWTOT * 4;
  float* scb    = (float*)ws;

  k_cvtw<<<576, 256, 0, stream>>>(w_qkv, w_proj, whq, whp);
  k_transx<<<BB * 24 * NPOS / 256, 256, 0, stream>>>(x, xt);
  k_pool<<<384, 256, 0, stream>>>(x, pooled);
  k_offsc<<<72, 256, 0, stream>>>(pooled, w_off, b_off, w_sc, b_sc, offb, scb);
  k_gemm16<<<dim3(NPOS / 128, 576 / 64, BB), 256, 0, stream>>>(whq, b_qkv, xt, qkv, 576, NPOS);
  k_sample<<<768, 256, 0, stream>>>(qkv, offb, scb, ksb, vsb);
  k_attn<<<BB * NWTOT * NHH, 256, 0, stream>>>(qkv, ksb, vsb, rpb, pin);
  k_gemm16<<<dim3(NPOS / 128, DIMC / 64, BB), 256, 0, stream>>>(whp, b_proj, pin, out, DIMC, NPOS);
}

// Round 3
// 114.880 us; speedup vs baseline: 3.4816x; 1.9160x over previous
//
#include <hip/hip_runtime.h>
#include <math.h>

// Problem constants (B=2, DIM=192, NH=6, HD=32, S=16, H=32, W=32, WS=4^3)
#define BB    2
#define DIMC  192
#define NHH   6
#define HDD   32
#define NPOS  16384              // S*H*W
#define NWTOT 256                // windows per batch
#define ATT_SCALE 0.17677669529663687f  // 32^-0.5

typedef _Float16 f16x8 __attribute__((ext_vector_type(8)));
typedef float f32x4 __attribute__((ext_vector_type(4)));

// ---------------------------------------------------------------------------
// 0a) fp32 -> fp16 weight conversion (w_qkv 576x192, w_proj 192x192)
__global__ void k_cvtw(const float* __restrict__ wq, const float* __restrict__ wp,
                       _Float16* __restrict__ whq, _Float16* __restrict__ whp) {
  int i = blockIdx.x * 256 + threadIdx.x;
  if (i < 576 * DIMC) whq[i] = (_Float16)wq[i];
  else {
    int j = i - 576 * DIMC;
    if (j < DIMC * DIMC) whp[j] = (_Float16)wp[j];
  }
}

// 0b) transpose x (B,192,16384) fp32 -> Xt (B,16384,192) fp16
__global__ void k_transx(const float* __restrict__ x, _Float16* __restrict__ xt) {
  int idx = blockIdx.x * 256 + threadIdx.x;   // [0, 2*24*16384)
  int p = idx & (NPOS - 1);
  int t = idx >> 14;
  int cseg = t % 24;
  int b = t / 24;
  if (b >= BB) return;
  const float* src = x + ((size_t)b * DIMC + cseg * 8) * NPOS + p;
  _Float16 v[8];
#pragma unroll
  for (int j = 0; j < 8; ++j) v[j] = (_Float16)src[(size_t)j * NPOS];
  *(uint4*)(xt + ((size_t)b * NPOS + p) * DIMC + cseg * 8) = *(uint4*)v;
}

// ---------------------------------------------------------------------------
// 1) window avg-pool + leaky relu
__global__ void k_pool(const float* __restrict__ x, float* __restrict__ pooled) {
  int idx = blockIdx.x * 256 + threadIdx.x;
  if (idx >= BB * DIMC * NWTOT) return;
  int wi = idx & 255;
  int bc = idx >> 8;
  int ws = wi >> 6, wh = (wi >> 3) & 7, ww = wi & 7;
  const float* xb = x + (size_t)bc * NPOS + (ws * 4) * 1024 + (wh * 4) * 32 + (ww * 4);
  float s = 0.f;
  for (int iz = 0; iz < 4; ++iz)
    for (int iy = 0; iy < 4; ++iy) {
      const float* r = xb + iz * 1024 + iy * 32;
      s += r[0] + r[1] + r[2] + r[3];
    }
  s *= (1.f / 64.f);
  pooled[idx] = (s >= 0.f) ? s : 0.01f * s;
}

// ---------------------------------------------------------------------------
// 2) offset / scale 1x1 convs on pooled
__global__ void k_offsc(const float* __restrict__ pooled,
                        const float* __restrict__ w_off, const float* __restrict__ b_off,
                        const float* __restrict__ w_sc, const float* __restrict__ b_sc,
                        float* __restrict__ off, float* __restrict__ sc) {
  int idx = blockIdx.x * 256 + threadIdx.x;
  if (idx >= BB * 2 * 18 * NWTOT) return;
  int wi = idx & 255;
  int t = idx >> 8;
  int o = t % 18; t /= 18;
  int kind = t & 1;
  int b = t >> 1;
  const float* wrow = (kind ? w_sc : w_off) + o * DIMC;
  float acc = (kind ? b_sc : b_off)[o];
  const float* pb = pooled + (size_t)b * DIMC * NWTOT + wi;
  for (int c = 0; c < DIMC; ++c) acc += wrow[c] * pb[(size_t)c * NWTOT];
  int nh = o / 3, c3 = o % 3;
  size_t dst = ((size_t)(b * NHH + nh) * 3 + c3) * NWTOT + wi;
  if (!kind) {
    acc *= (c3 == 2) ? 0.25f : 0.125f;
    off[dst] = acc;
  } else {
    sc[dst] = acc;
  }
}

// ---------------------------------------------------------------------------
// 3) fp16 MFMA GEMM:  Y[b](MxN) = A(MxK=192) @ Bm[b]^T + bias
//    F16OUT: write fp16 [b][n][ldm] (n-major, ch-contiguous), else fp32 [b][m][n].
template <bool F16OUT>
__global__ __launch_bounds__(256) void k_gemm16(
    const _Float16* __restrict__ A, const float* __restrict__ bias,
    const _Float16* __restrict__ Bm, float* __restrict__ Y32,
    _Float16* __restrict__ Y16, int M, int N, int ldm) {
  const int K = DIMC;
  int bz = blockIdx.z;
  int n0 = blockIdx.x * 128, m0 = blockIdx.y * 64;
  const _Float16* Bb = Bm + (size_t)bz * N * K;
  __shared__ _Float16 Al[64 * 64];    // swizzled [m][k]
  __shared__ _Float16 Bl[128 * 64];   // swizzled [n][k]
  int tid = threadIdx.x;
  int wave = tid >> 6, lane = tid & 63;
  int wm = wave >> 1, wn = wave & 1;
  int lrow = lane & 15, lkg = lane >> 4;
  f32x4 acc[2][4] = {};
  for (int k0 = 0; k0 < K; k0 += 64) {
    for (int c = tid; c < 512; c += 256) {
      int r = c >> 3, seg = c & 7;
      uint4 v = *(const uint4*)(A + (size_t)(m0 + r) * K + k0 + seg * 8);
      *(uint4*)((char*)Al + r * 128 + ((seg * 16) ^ ((r & 7) << 4))) = v;
    }
    for (int c = tid; c < 1024; c += 256) {
      int r = c >> 3, seg = c & 7;
      uint4 v = *(const uint4*)(Bb + (size_t)(n0 + r) * K + k0 + seg * 8);
      *(uint4*)((char*)Bl + r * 128 + ((seg * 16) ^ ((r & 7) << 4))) = v;
    }
    __syncthreads();
#pragma unroll
    for (int ks = 0; ks < 2; ++ks) {
      f16x8 af[2], bf[4];
#pragma unroll
      for (int mf = 0; mf < 2; ++mf) {
        int row = wm * 32 + mf * 16 + lrow;
        af[mf] = *(const f16x8*)((const char*)Al + row * 128 +
                                 ((ks * 64 + lkg * 16) ^ ((row & 7) << 4)));
      }
#pragma unroll
      for (int nf = 0; nf < 4; ++nf) {
        int row = wn * 64 + nf * 16 + lrow;
        bf[nf] = *(const f16x8*)((const char*)Bl + row * 128 +
                                 ((ks * 64 + lkg * 16) ^ ((row & 7) << 4)));
      }
#pragma unroll
      for (int mf = 0; mf < 2; ++mf)
#pragma unroll
        for (int nf = 0; nf < 4; ++nf)
          acc[mf][nf] = __builtin_amdgcn_mfma_f32_16x16x32_f16(af[mf], bf[nf], acc[mf][nf], 0, 0, 0);
    }
    __syncthreads();
  }
  int crow = lkg * 4, ccol = lrow;
#pragma unroll
  for (int mf = 0; mf < 2; ++mf)
#pragma unroll
    for (int nf = 0; nf < 4; ++nf) {
      int m = m0 + wm * 32 + mf * 16 + crow;
      int n = n0 + wn * 64 + nf * 16 + ccol;
      if (F16OUT) {
        union { _Float16 h[4]; uint2 u; } pk;
#pragma unroll
        for (int r = 0; r < 4; ++r) pk.h[r] = (_Float16)(acc[mf][nf][r] + bias[m + r]);
        *(uint2*)(Y16 + ((size_t)bz * N + n) * ldm + m) = pk.u;
      } else {
#pragma unroll
        for (int r = 0; r < 4; ++r)
          Y32[(size_t)bz * M * N + (size_t)(m + r) * N + n] = acc[mf][nf][r] + bias[m + r];
      }
    }
}

// ---------------------------------------------------------------------------
// 4) deformable grid-sample of K and V from fp16 qkv [b][pos][576].
//    Writes kw[bnh][win][tok][32hd] and vt[bnh][win][32hd][64tok] (fp16).
__global__ __launch_bounds__(256) void k_sample(
    const _Float16* __restrict__ qkvh,
    const float* __restrict__ off, const float* __restrict__ sc,
    _Float16* __restrict__ kw, _Float16* __restrict__ vt) {
  __shared__ char VT[4][4096];   // per-window [32hd][64tok] fp16, byte^((hd&7)<<4)
  int bnh = blockIdx.y; int b = bnh / NHH, nh = bnh % NHH;
  int tid = threadIdx.x;
  int wloc = tid >> 6, tok = tid & 63;
  int win = blockIdx.x * 4 + wloc;
  int is = tok >> 4, ih = (tok >> 2) & 3, iw = tok & 3;
  int s = (win >> 6) * 4 + is, h = ((win >> 3) & 7) * 4 + ih, w = (win & 7) * 4 + iw;
  const float* ob = off + ((size_t)bnh * 3) * NWTOT + win;
  const float* sb = sc + ((size_t)bnh * 3) * NWTOT + win;
  float gxn = -1.f + 2.f * w / 31.f + ((2.f * iw - 3.f) / 31.f) * sb[0] + ob[0];
  float gyn = -1.f + 2.f * h / 31.f + ((2.f * ih - 3.f) / 31.f) * sb[NWTOT] + ob[NWTOT];
  float gzn = -1.f + 2.f * s / 15.f + ((2.f * is - 3.f) / 15.f) * sb[2 * NWTOT] + ob[2 * NWTOT];
  float gx = (gxn + 1.f) * 15.5f;
  float gy = (gyn + 1.f) * 15.5f;
  float gz = (gzn + 1.f) * 7.5f;
  float x0f = floorf(gx), y0f = floorf(gy), z0f = floorf(gz);
  float fx = gx - x0f, fy = gy - y0f, fz = gz - z0f;
  int x0 = (int)x0f, y0 = (int)y0f, z0 = (int)z0f;
  int cidx[8];
  float cw[8];
  {
    int n = 0;
    for (int dz = 0; dz < 2; ++dz)
      for (int dy = 0; dy < 2; ++dy)
        for (int dx = 0; dx < 2; ++dx) {
          int zz = z0 + dz, yy = y0 + dy, xx = x0 + dx;
          bool valid = (zz >= 0 && zz < 16 && yy >= 0 && yy < 32 && xx >= 0 && xx < 32);
          int zc = min(max(zz, 0), 15), yc = min(max(yy, 0), 31), xc = min(max(xx, 0), 31);
          float wgt = (dz ? fz : 1.f - fz) * (dy ? fy : 1.f - fy) * (dx ? fx : 1.f - fx);
          cidx[n] = zc * 1024 + yc * 32 + xc;
          cw[n] = valid ? wgt : 0.f;
          ++n;
        }
  }
  float ak[4][8] = {}, av[4][8] = {};
#pragma unroll
  for (int j = 0; j < 8; ++j) {
    const f16x8* cp = (const f16x8*)(qkvh + ((size_t)b * NPOS + cidx[j]) * 576 + 192 + nh * 32);
    const f16x8* cv = (const f16x8*)(qkvh + ((size_t)b * NPOS + cidx[j]) * 576 + 384 + nh * 32);
    float wg = cw[j];
#pragma unroll
    for (int c = 0; c < 4; ++c) {
      f16x8 kv = cp[c], vv = cv[c];
#pragma unroll
      for (int t = 0; t < 8; ++t) {
        ak[c][t] += wg * (float)kv[t];
        av[c][t] += wg * (float)vv[t];
      }
    }
  }
  _Float16* kd = kw + (((size_t)bnh * 256 + win) * 64 + tok) * 32;
#pragma unroll
  for (int c = 0; c < 4; ++c) {
    union { _Float16 h[8]; uint4 u; } pk;
#pragma unroll
    for (int t = 0; t < 8; ++t) pk.h[t] = (_Float16)ak[c][t];
    *(uint4*)(kd + c * 8) = pk.u;
  }
  char* vb = VT[wloc];
#pragma unroll
  for (int c = 0; c < 4; ++c)
#pragma unroll
    for (int t = 0; t < 8; ++t) {
      int hd = c * 8 + t;
      *(_Float16*)(vb + hd * 128 + ((tok * 2) ^ ((hd & 7) << 4))) = (_Float16)av[c][t];
    }
  __syncthreads();
  int hd = tok >> 1, half = tok & 1;
  char* vr = VT[wloc] + hd * 128;
  uint4 q0 = *(uint4*)(vr + (((half * 4 + 0) ^ (hd & 7)) << 4));
  uint4 q1 = *(uint4*)(vr + (((half * 4 + 1) ^ (hd & 7)) << 4));
  uint4 q2 = *(uint4*)(vr + (((half * 4 + 2) ^ (hd & 7)) << 4));
  uint4 q3 = *(uint4*)(vr + (((half * 4 + 3) ^ (hd & 7)) << 4));
  _Float16* vd = vt + (((size_t)bnh * 256 + win) * 32 + hd) * 64 + half * 32;
  *(uint4*)(vd + 0)  = q0;
  *(uint4*)(vd + 8)  = q1;
  *(uint4*)(vd + 16) = q2;
  *(uint4*)(vd + 24) = q3;
}

// ---------------------------------------------------------------------------
// 5) windowed attention, MFMA. Block = 4 waves = 4 windows of one (b,nh).
//    S^T = mfma(K, Q); softmax per q-col; P -> swizzled per-wave LDS;
//    out^T = mfma(V^T, P^T); b64 stores assemble full 64B lines of pin.
__global__ __launch_bounds__(256) void k_attn(
    const _Float16* __restrict__ qkvh, const _Float16* __restrict__ kw,
    const _Float16* __restrict__ vt, const float* __restrict__ rpb_g,
    _Float16* __restrict__ pin) {
  __shared__ float biasT[64 * 68];    // [ktok][qtok], pad 68 -> 2-way max
  __shared__ char Pl[4][8192];        // per-wave P[q][ktok] fp16, swizzled
  int bnh = blockIdx.y; int b = bnh / NHH, nh = bnh % NHH;
  int tid = threadIdx.x;
  for (int i = tid; i < 4096; i += 256) {
    int kt = i >> 6, qt = i & 63;
    int d0 = (qt >> 4) - (kt >> 4) + 3;
    int d1 = ((qt >> 2) & 3) - ((kt >> 2) & 3) + 3;
    int d2 = (qt & 3) - (kt & 3) + 3;
    biasT[kt * 68 + qt] = rpb_g[(d0 * 11 + d1 * 7 + d2) * 6 + nh];
  }
  __syncthreads();
  int wave = tid >> 6, lane = tid & 63;
  int cl = lane & 15, g = lane >> 4;
  int win = blockIdx.x * 4 + wave;
  int pbase = ((win >> 6) * 4) * 1024 + (((win >> 3) & 7) * 4) * 32 + (win & 7) * 4;
  int prow = (cl >> 2) * 32 + (cl & 3);       // within-window (ih,iw) -> pos offset
  // Q B-frags (direct from qkv fp16 [pos][576]) and K A-frags (kw)
  f16x8 qf[4], kf[4];
  const _Float16* qbase = qkvh + ((size_t)b * NPOS) * 576 + nh * 32 + g * 8;
#pragma unroll
  for (int n = 0; n < 4; ++n)
    qf[n] = *(const f16x8*)(qbase + (size_t)(pbase + n * 1024 + prow) * 576);
  const _Float16* kwin = kw + ((size_t)bnh * 256 + win) * 64 * 32;
#pragma unroll
  for (int m = 0; m < 4; ++m)
    kf[m] = *(const f16x8*)(kwin + (m * 16 + cl) * 32 + g * 8);
  f32x4 accT[4][4] = {};
#pragma unroll
  for (int m = 0; m < 4; ++m)
#pragma unroll
    for (int n = 0; n < 4; ++n)
      accT[m][n] = __builtin_amdgcn_mfma_f32_16x16x32_f16(kf[m], qf[n], accT[m][n], 0, 0, 0);
  // scale + bias  (accT[m][n][ri] = S^T[kt = m*16+g*4+ri][qt = n*16+cl])
#pragma unroll
  for (int m = 0; m < 4; ++m)
#pragma unroll
    for (int n = 0; n < 4; ++n)
#pragma unroll
      for (int ri = 0; ri < 4; ++ri)
        accT[m][n][ri] = accT[m][n][ri] * ATT_SCALE +
                         biasT[(m * 16 + g * 4 + ri) * 68 + n * 16 + cl];
  // softmax over k (local 16 + shfl_xor 16,32), fold 1/sum into P
  char* pw = Pl[wave];
#pragma unroll
  for (int n = 0; n < 4; ++n) {
    float mx = -1e30f;
#pragma unroll
    for (int m = 0; m < 4; ++m)
#pragma unroll
      for (int ri = 0; ri < 4; ++ri) mx = fmaxf(mx, accT[m][n][ri]);
    mx = fmaxf(mx, __shfl_xor(mx, 16));
    mx = fmaxf(mx, __shfl_xor(mx, 32));
    float sm = 0.f;
#pragma unroll
    for (int m = 0; m < 4; ++m)
#pragma unroll
      for (int ri = 0; ri < 4; ++ri) {
        float e = __expf(accT[m][n][ri] - mx);
        accT[m][n][ri] = e;
        sm += e;
      }
    sm += __shfl_xor(sm, 16);
    sm += __shfl_xor(sm, 32);
    float inv = 1.f / sm;
    int q = n * 16 + cl;
    char* rowp = pw + q * 128;
#pragma unroll
    for (int m = 0; m < 4; ++m) {
      union { _Float16 h[4]; uint2 u; } pk;
#pragma unroll
      for (int ri = 0; ri < 4; ++ri) pk.h[ri] = (_Float16)(accT[m][n][ri] * inv);
      *(uint2*)(rowp + ((m * 32 + g * 8) ^ ((q & 7) << 4))) = pk.u;
    }
  }
  __syncthreads();
  // PV: out^T = V^T @ P^T
  const _Float16* vwin = vt + ((size_t)bnh * 256 + win) * 32 * 64;
  f32x4 accO[2][4] = {};
#pragma unroll
  for (int ks = 0; ks < 2; ++ks) {
    f16x8 va[2], pf[4];
#pragma unroll
    for (int m2 = 0; m2 < 2; ++m2)
      va[m2] = *(const f16x8*)(vwin + (m2 * 16 + cl) * 64 + ks * 32 + g * 8);
#pragma unroll
    for (int n = 0; n < 4; ++n) {
      int q = n * 16 + cl;
      pf[n] = *(const f16x8*)(pw + q * 128 + ((ks * 64 + g * 16) ^ ((q & 7) << 4)));
    }
#pragma unroll
    for (int m2 = 0; m2 < 2; ++m2)
#pragma unroll
      for (int n = 0; n < 4; ++n)
        accO[m2][n] = __builtin_amdgcn_mfma_f32_16x16x32_f16(va[m2], pf[n], accO[m2][n], 0, 0, 0);
  }
  // store: accO[m2][n][r] = out[q = n*16+cl][hd = m2*16+g*4+r]
  _Float16* pb = pin + ((size_t)b * NPOS) * DIMC + nh * 32 + g * 4;
#pragma unroll
  for (int n = 0; n < 4; ++n) {
    _Float16* dst = pb + (size_t)(pbase + n * 1024 + prow) * DIMC;
#pragma unroll
    for (int m2 = 0; m2 < 2; ++m2) {
      union { _Float16 h[4]; uint2 u; } pk;
#pragma unroll
      for (int r = 0; r < 4; ++r) pk.h[r] = (_Float16)accO[m2][n][r];
      *(uint2*)(dst + m2 * 16) = pk.u;
    }
  }
}

// ---------------------------------------------------------------------------
extern "C" void kernel_launch(void* const* d_in, const int* in_sizes, int n_in,
                              void* d_out, int out_size, void* d_ws, size_t ws_size,
                              hipStream_t stream) {
  const float* x      = (const float*)d_in[0];
  const float* w_qkv  = (const float*)d_in[2];
  const float* b_qkv  = (const float*)d_in[3];
  const float* w_off  = (const float*)d_in[4];
  const float* b_off  = (const float*)d_in[5];
  const float* w_sc   = (const float*)d_in[6];
  const float* b_sc   = (const float*)d_in[7];
  const float* w_proj = (const float*)d_in[8];
  const float* b_proj = (const float*)d_in[9];
  const float* rpb    = (const float*)d_in[10];
  float* out = (float*)d_out;
  char* wsp = (char*)d_ws;

  _Float16* qkvh = (_Float16*)wsp;                      wsp += (size_t)BB * NPOS * 576 * 2;
  _Float16* kwb  = (_Float16*)wsp;                      wsp += (size_t)BB * NHH * NWTOT * 64 * 32 * 2;
  _Float16* vtb  = (_Float16*)wsp;                      wsp += (size_t)BB * NHH * NWTOT * 32 * 64 * 2;
  _Float16* xt   = (_Float16*)wsp;                      wsp += (size_t)BB * NPOS * DIMC * 2;
  _Float16* pin  = xt;   // alias: xt dead after qkv GEMM; attn fully rewrites
  _Float16* whq  = (_Float16*)wsp;                      wsp += (size_t)576 * DIMC * 2;
  _Float16* whp  = (_Float16*)wsp;                      wsp += (size_t)DIMC * DIMC * 2;
  float* pooled  = (float*)wsp;                         wsp += (size_t)BB * DIMC * NWTOT * 4;
  float* offb    = (float*)wsp;                         wsp += (size_t)BB * NHH * 3 * NWTOT * 4;
  float* scb     = (float*)wsp;

  k_cvtw<<<576, 256, 0, stream>>>(w_qkv, w_proj, whq, whp);
  k_transx<<<BB * 24 * NPOS / 256, 256, 0, stream>>>(x, xt);
  k_pool<<<384, 256, 0, stream>>>(x, pooled);
  k_offsc<<<72, 256, 0, stream>>>(pooled, w_off, b_off, w_sc, b_sc, offb, scb);
  k_gemm16<true><<<dim3(NPOS / 128, 576 / 64, BB), 256, 0, stream>>>(
      whq, b_qkv, xt, nullptr, qkvh, 576, NPOS, 576);
  k_sample<<<dim3(64, BB * NHH), 256, 0, stream>>>(qkvh, offb, scb, kwb, vtb);
  k_attn<<<dim3(64, BB * NHH), 256, 0, stream>>>(qkvh, kwb, vtb, rpb, pin);
  k_gemm16<false><<<dim3(NPOS / 128, DIMC / 64, BB), 256, 0, stream>>>(
      whp, b_proj, pin, out, nullptr, DIMC, NPOS, DIMC);
}